// Round 4
// baseline (171.335 us; speedup 1.0000x reference)
//
#include <hip/hip_runtime.h>
#include <hip/hip_bf16.h>

#define NE 32
#define MM 1024
#define KK 512
#define NN 512
#define BM 128
#define BN 128
#define BK 32   // bf16 elems per LDS row = 64 B = 4 x 16B units, XOR-swizzled

typedef __attribute__((ext_vector_type(8))) short bf16x8;
typedef __attribute__((ext_vector_type(4))) float floatx4;

__device__ __forceinline__ short f2bf(float f) {
  union { __hip_bfloat16 b; short s; } u;
  u.b = __float2bfloat16(f);   // RNE
  return u.s;
}

// One item per block. XCD-aware mapping: blocks dispatch round-robin over the
// 8 XCDs (b -> XCD b&7, perf heuristic only), so XCD x owns experts
// {x, x+8, x+16, x+24}. Per-XCD items = 32 + 3*sum(vt) <= 128 = slots/XCD,
// structurally. GEMM tiles first (expert-major -> that expert's 1MB B stays
// in this XCD's 4MB L2), zero-fill stripes after.
extern "C" __global__ __launch_bounds__(256, 4)
void expert_gemm(const float* __restrict__ A, const float* __restrict__ B,
                 const int* __restrict__ cnts, float* __restrict__ C)
{
  const int xcd  = blockIdx.x & 7;
  const int slot = blockIdx.x >> 3;
  const int tid  = threadIdx.x;

  int e = -1, mt = 0, nt = 0;
  int acc = 0;
#pragma unroll
  for (int g = 0; g < 4; ++g) {
    int ee = xcd + (g << 3);
    int vt = (cnts[ee] + BM - 1) >> 7;
    int c4 = vt << 2;
    if (e < 0 && slot < acc + c4) { int r = slot - acc; e = ee; mt = r >> 2; nt = r & 3; }
    acc += c4;
  }
  if (e < 0) {
    int z = slot - acc, a2 = 0;
#pragma unroll
    for (int g = 0; g < 4; ++g) {
      int ee = xcd + (g << 3);
      int vt = (cnts[ee] + BM - 1) >> 7;
      int c = 8 - vt;
      if (e < 0 && z < a2 + c) { e = ee; mt = vt + (z - a2); }
      a2 += c;
    }
    if (e < 0) return;   // beyond this XCD's item count
    // zero-fill a 128x512 stripe (harness poisons d_out to 0xAA each launch)
    float* Ce = C + ((size_t)e * MM + mt * BM) * NN;
    float4 zf = make_float4(0.f, 0.f, 0.f, 0.f);
#pragma unroll
    for (int i = 0; i < 64; ++i) {
      int fidx = i * 256 + tid;
      int r = fidx >> 7, c = (fidx & 127) << 2;
      *(float4*)(Ce + (size_t)r * NN + c) = zf;
    }
    return;
  }

  // ---- GEMM tile: C[e][m0:m0+128][n0:n0+128] = A[e] @ B[e]^T ----
  const int m0 = mt * BM, n0 = nt * BN;
  const int cnt = cnts[e];
  const float* Ae = A + ((size_t)e * MM + m0) * KK;
  const float* Be = B + ((size_t)e * NN + n0) * KK;
  float* Ce = C + ((size_t)e * MM + m0) * NN + n0;

  // Swizzled LDS: row r = 64 B = 4 units of 16 B; unit u stored at physical
  // unit (r*4 + (u ^ (r&3))). ds_write_b128/ds_read_b128 both conflict-free
  // (<=2-way, which is free per m136).
  __shared__ __align__(16) short lA[BM * BK];  // 8 KB
  __shared__ __align__(16) short lB[BN * BK];  // 8 KB

  const int wave = tid >> 6, lane = tid & 63;
  const int wm = (wave >> 1) * 64, wn = (wave & 1) * 64;
  const int fr = lane & 15, kh = lane >> 4;

  const int srow = tid >> 2;   // staging row (0..63; +64 on pass 1)
  const int su   = tid & 3;    // 16B unit within row -> floats [su*8, su*8+8)

  floatx4 acc4[4][4] = {};

  // software pipeline: prefetch K-slab 0 into registers
  float4 pa0[2], pa1[2], pb0[2], pb1[2];
#pragma unroll
  for (int p = 0; p < 2; ++p) {
    int row = srow + (p << 6);
    int col = su << 3;
    pa0[p] = *(const float4*)(Ae + (size_t)row * KK + col);
    pa1[p] = *(const float4*)(Ae + (size_t)row * KK + col + 4);
    pb0[p] = *(const float4*)(Be + (size_t)row * KK + col);
    pb1[p] = *(const float4*)(Be + (size_t)row * KK + col + 4);
  }

  for (int kt = 0; kt < KK; kt += BK) {
    __syncthreads();   // previous iteration's ds_reads complete before overwrite
#pragma unroll
    for (int p = 0; p < 2; ++p) {
      int row = srow + (p << 6);
      int unit = (row << 2) + (su ^ (row & 3));
      bf16x8 va = { f2bf(pa0[p].x), f2bf(pa0[p].y), f2bf(pa0[p].z), f2bf(pa0[p].w),
                    f2bf(pa1[p].x), f2bf(pa1[p].y), f2bf(pa1[p].z), f2bf(pa1[p].w) };
      bf16x8 vb = { f2bf(pb0[p].x), f2bf(pb0[p].y), f2bf(pb0[p].z), f2bf(pb0[p].w),
                    f2bf(pb1[p].x), f2bf(pb1[p].y), f2bf(pb1[p].z), f2bf(pb1[p].w) };
      *(bf16x8*)(lA + (unit << 3)) = va;
      *(bf16x8*)(lB + (unit << 3)) = vb;
    }
    __syncthreads();

    // issue next slab's loads NOW — latency hides behind ds_reads + 16 MFMAs
    if (kt + BK < KK) {
#pragma unroll
      for (int p = 0; p < 2; ++p) {
        int row = srow + (p << 6);
        int col = kt + BK + (su << 3);
        pa0[p] = *(const float4*)(Ae + (size_t)row * KK + col);
        pa1[p] = *(const float4*)(Ae + (size_t)row * KK + col + 4);
        pb0[p] = *(const float4*)(Be + (size_t)row * KK + col);
        pb1[p] = *(const float4*)(Be + (size_t)row * KK + col + 4);
      }
    }

    bf16x8 af[4], bfv[4];
#pragma unroll
    for (int i = 0; i < 4; ++i) {
      int rA = wm + (i << 4) + fr;
      af[i]  = *(const bf16x8*)(lA + ((((rA << 2) + (kh ^ (rA & 3)))) << 3));
      int rB = wn + (i << 4) + fr;
      bfv[i] = *(const bf16x8*)(lB + ((((rB << 2) + (kh ^ (rB & 3)))) << 3));
    }
#pragma unroll
    for (int i = 0; i < 4; ++i)
#pragma unroll
      for (int j = 0; j < 4; ++j)
        acc4[i][j] = __builtin_amdgcn_mfma_f32_16x16x32_bf16(af[i], bfv[j], acc4[i][j], 0, 0, 0);
  }

  // epilogue: C/D layout col=lane&15, row=(lane>>4)*4+reg (m89/m91-verified)
  const int rb_ = (lane >> 4) * 4;
#pragma unroll
  for (int i = 0; i < 4; ++i) {
#pragma unroll
    for (int r = 0; r < 4; ++r) {
      int row = wm + i * 16 + rb_ + r;
      bool valid = (m0 + row) < cnt;
#pragma unroll
      for (int j = 0; j < 4; ++j) {
        int col = wn + j * 16 + fr;
        Ce[(size_t)row * NN + col] = valid ? acc4[i][j][r] : 0.0f;
      }
    }
  }
}

extern "C" void kernel_launch(void* const* d_in, const int* in_sizes, int n_in,
                              void* d_out, int out_size, void* d_ws, size_t ws_size,
                              hipStream_t stream) {
  const float* A    = (const float*)d_in[0];
  const float* B    = (const float*)d_in[1];
  const int*   cnts = (const int*)d_in[2];
  float*       C    = (float*)d_out;

  hipLaunchKernelGGL(expert_gemm, dim3(1024), dim3(256), 0, stream, A, B, cnts, C);
}

// Round 5
// 160.289 us; speedup vs baseline: 1.0689x; 1.0689x over previous
//
#include <hip/hip_runtime.h>
#include <hip/hip_bf16.h>

#define NE 32
#define MM 1024
#define KK 512
#define NN 512
#define BM 128
#define BN 128
#define BK 32          // bf16 elems per LDS row = 64 B = 4 x 16B units, XOR-swizzled
#define NS (KK / BK)   // 16 K-slabs

typedef __attribute__((ext_vector_type(8))) short bf16x8;
typedef __attribute__((ext_vector_type(4))) float floatx4;

__device__ __forceinline__ short f2bf(float f) {
  union { __hip_bfloat16 b; short s; } u;
  u.b = __float2bfloat16(f);   // RNE
  return u.s;
}

// One item per block, decoded from cnts. Zero-fill stripes occupy LOW block
// indices (retire in ~1us, freeing CU slots so the 256-block backfill pool of
// GEMM tiles balances dynamically); GEMM tiles follow, expert-major.
// total items = 256 + 3*sum(vt) <= 1024 = grid, structurally.
extern "C" __global__ __launch_bounds__(256, 3)
void expert_gemm(const float* __restrict__ A, const float* __restrict__ B,
                 const int* __restrict__ cnts, float* __restrict__ C)
{
  const int b   = blockIdx.x;
  const int tid = threadIdx.x;

  int e = -1, mt = 0, nt = 0;
  int acc = 0;
#pragma unroll 1
  for (int i = 0; i < NE; ++i) {           // zero-stripe items first
    int vt = (cnts[i] + BM - 1) >> 7;
    int c = 8 - vt;
    if (e < 0 && b < acc + c) { e = i; mt = vt + (b - acc); }
    acc += c;
  }
  if (e >= 0) {
    // zero-fill a 128x512 stripe (harness poisons d_out to 0xAA each launch)
    float* Ce = C + ((size_t)e * MM + mt * BM) * NN;
    float4 zf = make_float4(0.f, 0.f, 0.f, 0.f);
#pragma unroll
    for (int i = 0; i < 64; ++i) {
      int fidx = i * 256 + tid;
      int r = fidx >> 7, c = (fidx & 127) << 2;
      *(float4*)(Ce + (size_t)r * NN + c) = zf;
    }
    return;
  }
  int g = b - acc;
  acc = 0;
#pragma unroll 1
  for (int i = 0; i < NE; ++i) {           // GEMM tile items
    int vt = (cnts[i] + BM - 1) >> 7;
    int c4 = vt << 2;
    if (e < 0 && g < acc + c4) { int r = g - acc; e = i; mt = r >> 2; nt = r & 3; }
    acc += c4;
  }
  if (e < 0) return;                       // beyond total item count

  // ---- GEMM tile: C[e][m0:m0+128][n0:n0+128] = A[e] @ B[e]^T ----
  const int m0 = mt * BM, n0 = nt * BN;
  const int cnt = cnts[e];
  const float* Ae = A + ((size_t)e * MM + m0) * KK;
  const float* Be = B + ((size_t)e * NN + n0) * KK;
  float* Ce = C + ((size_t)e * MM + m0) * NN + n0;

  // Double-buffered, XOR-swizzled LDS: row r = 64 B = 4 units of 16 B; unit u
  // stored at physical unit (r*4 + (u ^ (r&3))) -> conflict-free b128 ops.
  __shared__ __align__(16) short lA[2][BM * BK];  // 2 x 8 KB
  __shared__ __align__(16) short lB[2][BN * BK];  // 2 x 8 KB

  const int wave = tid >> 6, lane = tid & 63;
  const int wm = (wave >> 1) * 64, wn = (wave & 1) * 64;
  const int fr = lane & 15, kh = lane >> 4;
  const int srow = tid >> 2;   // staging row (0..63; +64 on pass 1)
  const int su   = tid & 3;    // 16B unit within row -> floats [su*8, su*8+8)

  floatx4 acc4[4][4] = {};

  // prologue: issue slab-0 loads (held in regs until consumed next phase)
  float4 pa0[2], pa1[2], pb0[2], pb1[2];
#pragma unroll
  for (int p = 0; p < 2; ++p) {
    int row = srow + (p << 6);
    int col = su << 3;
    pa0[p] = *(const float4*)(Ae + (size_t)row * KK + col);
    pa1[p] = *(const float4*)(Ae + (size_t)row * KK + col + 4);
    pb0[p] = *(const float4*)(Be + (size_t)row * KK + col);
    pb1[p] = *(const float4*)(Be + (size_t)row * KK + col + 4);
  }

#pragma unroll 1
  for (int s = 0; s < NS; ++s) {
    short* bufA = &lA[s & 1][0];
    short* bufB = &lB[s & 1][0];

    // (1) convert slab s (vmcnt wait — loads are one full iteration old) + write
#pragma unroll
    for (int p = 0; p < 2; ++p) {
      int row = srow + (p << 6);
      int unit = (row << 2) + (su ^ (row & 3));
      bf16x8 va = { f2bf(pa0[p].x), f2bf(pa0[p].y), f2bf(pa0[p].z), f2bf(pa0[p].w),
                    f2bf(pa1[p].x), f2bf(pa1[p].y), f2bf(pa1[p].z), f2bf(pa1[p].w) };
      bf16x8 vb = { f2bf(pb0[p].x), f2bf(pb0[p].y), f2bf(pb0[p].z), f2bf(pb0[p].w),
                    f2bf(pb1[p].x), f2bf(pb1[p].y), f2bf(pb1[p].z), f2bf(pb1[p].w) };
      *(bf16x8*)(bufA + (unit << 3)) = va;
      *(bf16x8*)(bufB + (unit << 3)) = vb;
    }
    // (2) one barrier per slab: separates this buffer's writes from its reads,
    //     and last iter's reads of the OTHER buffer from its next writes.
    __syncthreads();

    // (3) issue slab s+1 loads now; latency hides behind the MFMA block below
    if (s + 1 < NS) {
      int col = (s + 1) * BK + (su << 3);
#pragma unroll
      for (int p = 0; p < 2; ++p) {
        int row = srow + (p << 6);
        pa0[p] = *(const float4*)(Ae + (size_t)row * KK + col);
        pa1[p] = *(const float4*)(Ae + (size_t)row * KK + col + 4);
        pb0[p] = *(const float4*)(Be + (size_t)row * KK + col);
        pb1[p] = *(const float4*)(Be + (size_t)row * KK + col + 4);
      }
    }
    __builtin_amdgcn_sched_barrier(0);   // pin load-issue above the MFMA block

    // (4) fragments + 16 MFMAs from buf[s&1]
    bf16x8 af[4], bfv[4];
#pragma unroll
    for (int i = 0; i < 4; ++i) {
      int rA = wm + (i << 4) + fr;
      af[i]  = *(const bf16x8*)(bufA + ((((rA << 2) + (kh ^ (rA & 3)))) << 3));
      int rB = wn + (i << 4) + fr;
      bfv[i] = *(const bf16x8*)(bufB + ((((rB << 2) + (kh ^ (rB & 3)))) << 3));
    }
#pragma unroll
    for (int i = 0; i < 4; ++i)
#pragma unroll
      for (int j = 0; j < 4; ++j)
        acc4[i][j] = __builtin_amdgcn_mfma_f32_16x16x32_bf16(af[i], bfv[j], acc4[i][j], 0, 0, 0);
  }

  // epilogue: C/D layout col=lane&15, row=(lane>>4)*4+reg (m89/m91-verified)
  const int rb_ = (lane >> 4) * 4;
#pragma unroll
  for (int i = 0; i < 4; ++i) {
#pragma unroll
    for (int r = 0; r < 4; ++r) {
      int row = wm + i * 16 + rb_ + r;
      bool valid = (m0 + row) < cnt;
#pragma unroll
      for (int j = 0; j < 4; ++j) {
        int col = wn + j * 16 + fr;
        Ce[(size_t)row * NN + col] = valid ? acc4[i][j][r] : 0.0f;
      }
    }
  }
}

extern "C" void kernel_launch(void* const* d_in, const int* in_sizes, int n_in,
                              void* d_out, int out_size, void* d_ws, size_t ws_size,
                              hipStream_t stream) {
  const float* A    = (const float*)d_in[0];
  const float* B    = (const float*)d_in[1];
  const int*   cnts = (const int*)d_in[2];
  float*       C    = (float*)d_out;

  hipLaunchKernelGGL(expert_gemm, dim3(1024), dim3(256), 0, stream, A, B, cnts, C);
}